// Round 24
// baseline (89.762 us; speedup 1.0000x reference)
//
#include <hip/hip_runtime.h>

#define NN 100000
#define EE 1600000
#define INC 128
#define OUTC 64
#define NEG_SLOPE 0.2f

#define BSH 7                 // bucket = dst >> 7 (128 nodes/bucket)
#define BNODES 128
#define NB 782                // ceil(NN/128)
#define BCAP 2560             // padded bucket capacity (mean 2048, +11 sigma)
#define CHUNKA 4096           // edges per bin-role block (256 threads x 16)
#define NBLKA 391             // ceil(EE/CHUNKA)
#define NBLKG (NB + NBLKA)    // merged grid: 782 gemm + 391 bin = 1173
#define NSLOT 5               // k_sa sort-phase register slots: 5*512 = 2560 = BCAP

typedef __attribute__((ext_vector_type(8))) short bf16x8;
typedef __attribute__((ext_vector_type(4))) float f32x4;

__device__ __forceinline__ unsigned short f2bf(float f) {
  unsigned u = __float_as_uint(f);
  unsigned r = (u + 0x7fffu + ((u >> 16) & 1u)) >> 16;  // RNE
  return (unsigned short)r;
}
__device__ __forceinline__ float bf2f(unsigned u16) {
  return __uint_as_float(u16 << 16);
}

// ---------------- K0: zero bucket cursors (must precede k_gb's bin role) -------
__global__ __launch_bounds__(256) void k_zero(int* __restrict__ gcursor) {
  for (int i = threadIdx.x; i < NB; i += 256) gcursor[i] = 0;
}

// ---------------- K1: gemm-role || bin-role, INTERLEAVED ------------------------
// R23 lesson: k_gb was LDS-capacity-starved (44.2KB union -> 2 blocks/CU, ~25%
// occupancy, latency-bound at ~2 TB/s). Fix: bin stage split into uint packed
// word + ushort bucket id (24KB vs 32KB uint2) -> union 35.9KB -> 4 blocks/CU.
// Burst lengths (CHUNKA=4096) unchanged.
__global__ __launch_bounds__(256)
__attribute__((amdgpu_waves_per_eu(1, 3)))
void k_gb(
    const float* __restrict__ x, const float* __restrict__ W,
    const float* __restrict__ a, unsigned short* __restrict__ Wxh,
    float* __restrict__ s_i, float* __restrict__ s_j,
    const int* __restrict__ src, const int* __restrict__ dst,
    int* __restrict__ gcursor, unsigned* __restrict__ binned)
{
  __shared__ __align__(16) char smem[35904];   // union: gemm 18.4KB | bin 35.9KB
  const int t = threadIdx.x;
  const int bid = blockIdx.x;
  const bool isBin = (bid % 3 == 2);

  if (!isBin) {
    // ================= gemm role: Wx = x @ W^T via MFMA, s_i/s_j fused =======
    const int gi = (bid / 3) * 2 + (bid % 3);   // 0..781, each exactly once
    unsigned short (*hs)[32][72] = reinterpret_cast<unsigned short(*)[32][72]>(smem);
    const int w = t >> 6;
    const int l = t & 63;
    const int lr = l & 15;
    const int lk = l >> 4;
    const int row0 = gi * 128 + w * 32;

    f32x4 acc[2][4];
    #pragma unroll
    for (int m = 0; m < 2; ++m)
      #pragma unroll
      for (int n = 0; n < 4; ++n) acc[m][n] = (f32x4){0.f, 0.f, 0.f, 0.f};

    #pragma unroll
    for (int ks = 0; ks < 4; ++ks) {
      const int k0 = ks * 32 + lk * 8;
      bf16x8 af[2], bfr[4];
      #pragma unroll
      for (int m = 0; m < 2; ++m) {
        int r = row0 + m * 16 + lr;
        r = (r < NN) ? r : (NN - 1);
        const float* p = &x[(size_t)r * INC + k0];
        float4 u0 = *reinterpret_cast<const float4*>(p);
        float4 u1 = *reinterpret_cast<const float4*>(p + 4);
        af[m][0] = (short)f2bf(u0.x); af[m][1] = (short)f2bf(u0.y);
        af[m][2] = (short)f2bf(u0.z); af[m][3] = (short)f2bf(u0.w);
        af[m][4] = (short)f2bf(u1.x); af[m][5] = (short)f2bf(u1.y);
        af[m][6] = (short)f2bf(u1.z); af[m][7] = (short)f2bf(u1.w);
      }
      #pragma unroll
      for (int n = 0; n < 4; ++n) {
        int c = n * 16 + lr;
        const float* p = &W[(size_t)c * INC + k0];
        float4 u0 = *reinterpret_cast<const float4*>(p);
        float4 u1 = *reinterpret_cast<const float4*>(p + 4);
        bfr[n][0] = (short)f2bf(u0.x); bfr[n][1] = (short)f2bf(u0.y);
        bfr[n][2] = (short)f2bf(u0.z); bfr[n][3] = (short)f2bf(u0.w);
        bfr[n][4] = (short)f2bf(u1.x); bfr[n][5] = (short)f2bf(u1.y);
        bfr[n][6] = (short)f2bf(u1.z); bfr[n][7] = (short)f2bf(u1.w);
      }
      #pragma unroll
      for (int m = 0; m < 2; ++m)
        #pragma unroll
        for (int n = 0; n < 4; ++n)
          acc[m][n] = __builtin_amdgcn_mfma_f32_16x16x32_bf16(af[m], bfr[n], acc[m][n], 0, 0, 0);
    }

    // fused score dots
    float a1[4], a2[4];
    #pragma unroll
    for (int n = 0; n < 4; ++n) {
      a1[n] = a[n * 16 + lr];
      a2[n] = a[OUTC + n * 16 + lr];
    }
    #pragma unroll
    for (int m = 0; m < 2; ++m)
      #pragma unroll
      for (int r = 0; r < 4; ++r) {
        float p1 = 0.f, p2 = 0.f;
        #pragma unroll
        for (int n = 0; n < 4; ++n) {
          p1 = fmaf(acc[m][n][r], a1[n], p1);
          p2 = fmaf(acc[m][n][r], a2[n], p2);
        }
        #pragma unroll
        for (int mm = 1; mm < 16; mm <<= 1) {
          p1 += __shfl_xor(p1, mm);
          p2 += __shfl_xor(p2, mm);
        }
        int rr = row0 + m * 16 + lk * 4 + r;
        if (lr == 0 && rr < NN) { s_i[rr] = p1; s_j[rr] = p2; }
      }

    // bf16 Wx store via per-wave LDS bounce -> coalesced uint4 stores
    #pragma unroll
    for (int m = 0; m < 2; ++m)
      #pragma unroll
      for (int n = 0; n < 4; ++n)
        #pragma unroll
        for (int r = 0; r < 4; ++r)
          hs[w][m * 16 + lk * 4 + r][n * 16 + lr] = f2bf(acc[m][n][r]);
    __syncthreads();
    #pragma unroll
    for (int j = 0; j < 4; ++j) {
      int idx = j * 64 + l;
      int rr = idx >> 3;
      int c8 = idx & 7;
      int node = row0 + rr;
      if (node < NN) {
        uint4 v = *reinterpret_cast<const uint4*>(&hs[w][rr][c8 * 8]);
        *reinterpret_cast<uint4*>(&Wxh[(size_t)node * OUTC + c8 * 8]) = v;
      }
    }
  } else {
    // ================= bin role: bucket-bin 4096 edges (burst writes) ========
    // Packed word: src (17b) | dl (7b) << 17. Rank-from-histogram.
    // Stage split: stage_pk (uint) + stage_bk (ushort bucket) = 24KB (was 32).
    const int bi = bid / 3;                  // 0..390
    int* lh = reinterpret_cast<int*>(smem);                       // 4096 B
    int* ls = lh + 1024;                                          // 4096 B
    int* gb = ls + 1024;                                          // 3136 B
    unsigned* stage_pk = reinterpret_cast<unsigned*>(smem + 11328);        // 16384 B
    unsigned short* stage_bk = reinterpret_cast<unsigned short*>(smem + 27712);  // 8192 B
    __shared__ int wsum[4];
    const int c0 = bi * CHUNKA;
    const int cend = min(c0 + CHUNKA, EE);
    const int total = cend - c0;

    #pragma unroll
    for (int k = 0; k < 4; ++k) lh[t + k * 256] = 0;
    __syncthreads();

    int esrc[16], edst[16], rnk[16];
    #pragma unroll
    for (int k = 0; k < 16; ++k) {
      int i = c0 + t + k * 256;
      bool v = i < cend;
      esrc[k] = v ? src[i] : -1;
      edst[k] = v ? dst[i] : -1;
      rnk[k] = v ? atomicAdd(&lh[edst[k] >> BSH], 1) : 0;
    }
    __syncthreads();

    // exclusive scan of 1024 cells: thread owns cells 4t..4t+3; wave shfl scan
    {
      int a0 = lh[4 * t], a1 = lh[4 * t + 1], a2 = lh[4 * t + 2], a3 = lh[4 * t + 3];
      int s4 = a0 + a1 + a2 + a3;
      int incl = s4;
      #pragma unroll
      for (int d = 1; d < 64; d <<= 1) {
        int u = __shfl_up(incl, d);
        if ((t & 63) >= d) incl += u;
      }
      if ((t & 63) == 63) wsum[t >> 6] = incl;
      __syncthreads();
      int wv = t >> 6;
      int wbase = 0;
      #pragma unroll
      for (int k = 0; k < 4; ++k) wbase += (k < wv) ? wsum[k] : 0;
      int ex = wbase + incl - s4;
      ls[4 * t] = ex;
      ls[4 * t + 1] = ex + a0;
      ls[4 * t + 2] = ex + a0 + a1;
      ls[4 * t + 3] = ex + a0 + a1 + a2;
    }
    __syncthreads();

    #pragma unroll
    for (int k = 0; k < 16; ++k) {
      if (edst[k] >= 0) {
        int bb = edst[k] >> BSH;
        int p = ls[bb] + rnk[k];
        stage_pk[p] = (unsigned)esrc[k] | ((unsigned)(edst[k] & (BNODES - 1)) << 17);
        stage_bk[p] = (unsigned short)bb;
      }
    }
    __syncthreads();

    for (int b = t; b < NB; b += 256) {
      int cnt = lh[b];
      if (cnt) gb[b] = atomicAdd(&gcursor[b], cnt);
    }
    __syncthreads();

    // consecutive i -> same bucket -> coalesced full-line bursts
    for (int i = t; i < total; i += 256) {
      int b = (int)stage_bk[i];
      int idx = gb[b] + (i - ls[b]);
      if (idx < BCAP) binned[b * BCAP + idx] = stage_pk[i];  // clamp: never corrupt neighbors
    }
  }
}

// ---------------- K2: FUSED per-bucket sort + aggregate + ELU ------------------
// Phase 1: rank-from-histogram scatter of packed (alpha|src) into LDS stage.
// Phase 2: 16 half-waves x 8 rounds; 4 quad-groups x 4 edges in flight per
// node (lane = 8 channels), shfl_xor(8,16) reduce. 512 threads (R22 lesson).
// R23 lesson: k_sa is at its random-gather pattern floor (~2.2 TB/s) -- more
// occupancy does not help; kernel kept as-is.
__global__ __launch_bounds__(512) void k_sa(const int* __restrict__ gcursor,
                                            const unsigned* __restrict__ binned,
                                            const float* __restrict__ s_i,
                                            const float* __restrict__ s_j,
                                            const unsigned short* __restrict__ Wxh,
                                            float* __restrict__ out) {
  __shared__ int cnt128[BNODES];
  __shared__ int ex128[BNODES];
  __shared__ float sil[BNODES];
  __shared__ float den[BNODES];
  __shared__ float invd[BNODES];
  __shared__ unsigned stage[BCAP];
  __shared__ int sW0;
  const int t = threadIdx.x;
  const int b = blockIdx.x;
  const int n0 = b << BSH;
  const int base = b * BCAP;
  const int cnt = min(gcursor[b], BCAP);

  if (t < BNODES) {
    cnt128[t] = 0;
    den[t] = 0.f;
    int n = n0 + t;
    sil[t] = (n < NN) ? s_i[n] : 0.f;
  }
  __syncthreads();

  // ---- phase 1: load + rank + weight + denom (register-staged) ----
  unsigned es[NSLOT];
  int ed[NSLOT], rk[NSLOT];
  float ws[NSLOT];
  #pragma unroll
  for (int k = 0; k < NSLOT; ++k) {
    int i = t + k * 512;
    bool v = i < cnt;
    unsigned pw = v ? binned[base + i] : 0u;
    es[k] = pw & 0x1ffffu;
    ed[k] = v ? (int)(pw >> 17) : -1;
    ws[k] = 0.f;
    rk[k] = 0;
    if (v) {
      rk[k] = atomicAdd(&cnt128[ed[k]], 1);
      float sc = sil[ed[k]] + s_j[es[k]];
      sc = (sc > 0.f) ? sc : NEG_SLOPE * sc;
      ws[k] = __expf(sc);
      atomicAdd(&den[ed[k]], ws[k]);
    }
  }
  __syncthreads();

  // inverse denom + exclusive scan of counts via 2-wave shfl scan (t < 128)
  int c0 = 0;
  if (t < BNODES) {
    float dv = den[t];
    invd[t] = (dv > 0.f) ? 1.f / dv : 0.f;
    c0 = cnt128[t];
  }
  int incl = c0;
  #pragma unroll
  for (int d = 1; d < 64; d <<= 1) {
    int u = __shfl_up(incl, d);
    if ((t & 63) >= d) incl += u;
  }
  if (t == 63) sW0 = incl;
  __syncthreads();
  if (t < BNODES) ex128[t] = incl - c0 + ((t >= 64) ? sW0 : 0);
  __syncthreads();

  // scatter packed (alpha_hi15 | src) into node-sorted LDS order
  #pragma unroll
  for (int k = 0; k < NSLOT; ++k) {
    if (ed[k] >= 0) {
      float alpha = ws[k] * invd[ed[k]];
      unsigned abits = (__float_as_uint(alpha) + 0x10000u) & 0xfffe0000u;  // RNE to 15b
      stage[ex128[ed[k]] + rk[k]] = abits | es[k];
    }
  }
  __syncthreads();

  // ---- phase 2: 16 half-waves x 8 rounds; 4 edges x 4 quads in flight ----
  const int half = t >> 5;           // 0..15
  const int l32 = t & 31;
  const int g = l32 >> 3;            // quad slot 0..3
  const unsigned cl8 = (l32 & 7) << 3;  // channel octet base

  for (int rnd = 0; rnd < 8; ++rnd) {
    const int dl = rnd * 16 + half;
    const int myCnt = cnt128[dl];
    const int myEx = ex128[dl];
    float acc[8];
    #pragma unroll
    for (int j = 0; j < 8; ++j) acc[j] = 0.f;

    for (int eb = 0; eb < myCnt; eb += 16) {
      int i0 = eb + 4 * g;
      unsigned u0 = (i0 + 0 < myCnt) ? stage[myEx + i0 + 0] : 0u;
      unsigned u1 = (i0 + 1 < myCnt) ? stage[myEx + i0 + 1] : 0u;
      unsigned u2 = (i0 + 2 < myCnt) ? stage[myEx + i0 + 2] : 0u;
      unsigned u3 = (i0 + 3 < myCnt) ? stage[myEx + i0 + 3] : 0u;
      float w0 = __uint_as_float(u0 & 0xfffe0000u);   // pads: +0.0, src 0 (safe)
      float w1 = __uint_as_float(u1 & 0xfffe0000u);
      float w2 = __uint_as_float(u2 & 0xfffe0000u);
      float w3 = __uint_as_float(u3 & 0xfffe0000u);
      uint4 h0 = *reinterpret_cast<const uint4*>(&Wxh[((u0 & 0x1ffffu) << 6) + cl8]);
      uint4 h1 = *reinterpret_cast<const uint4*>(&Wxh[((u1 & 0x1ffffu) << 6) + cl8]);
      uint4 h2 = *reinterpret_cast<const uint4*>(&Wxh[((u2 & 0x1ffffu) << 6) + cl8]);
      uint4 h3 = *reinterpret_cast<const uint4*>(&Wxh[((u3 & 0x1ffffu) << 6) + cl8]);
      acc[0] = fmaf(w0, bf2f(h0.x & 0xffffu), acc[0]);
      acc[1] = fmaf(w0, bf2f(h0.x >> 16), acc[1]);
      acc[2] = fmaf(w0, bf2f(h0.y & 0xffffu), acc[2]);
      acc[3] = fmaf(w0, bf2f(h0.y >> 16), acc[3]);
      acc[4] = fmaf(w0, bf2f(h0.z & 0xffffu), acc[4]);
      acc[5] = fmaf(w0, bf2f(h0.z >> 16), acc[5]);
      acc[6] = fmaf(w0, bf2f(h0.w & 0xffffu), acc[6]);
      acc[7] = fmaf(w0, bf2f(h0.w >> 16), acc[7]);
      acc[0] = fmaf(w1, bf2f(h1.x & 0xffffu), acc[0]);
      acc[1] = fmaf(w1, bf2f(h1.x >> 16), acc[1]);
      acc[2] = fmaf(w1, bf2f(h1.y & 0xffffu), acc[2]);
      acc[3] = fmaf(w1, bf2f(h1.y >> 16), acc[3]);
      acc[4] = fmaf(w1, bf2f(h1.z & 0xffffu), acc[4]);
      acc[5] = fmaf(w1, bf2f(h1.z >> 16), acc[5]);
      acc[6] = fmaf(w1, bf2f(h1.w & 0xffffu), acc[6]);
      acc[7] = fmaf(w1, bf2f(h1.w >> 16), acc[7]);
      acc[0] = fmaf(w2, bf2f(h2.x & 0xffffu), acc[0]);
      acc[1] = fmaf(w2, bf2f(h2.x >> 16), acc[1]);
      acc[2] = fmaf(w2, bf2f(h2.y & 0xffffu), acc[2]);
      acc[3] = fmaf(w2, bf2f(h2.y >> 16), acc[3]);
      acc[4] = fmaf(w2, bf2f(h2.z & 0xffffu), acc[4]);
      acc[5] = fmaf(w2, bf2f(h2.z >> 16), acc[5]);
      acc[6] = fmaf(w2, bf2f(h2.w & 0xffffu), acc[6]);
      acc[7] = fmaf(w2, bf2f(h2.w >> 16), acc[7]);
      acc[0] = fmaf(w3, bf2f(h3.x & 0xffffu), acc[0]);
      acc[1] = fmaf(w3, bf2f(h3.x >> 16), acc[1]);
      acc[2] = fmaf(w3, bf2f(h3.y & 0xffffu), acc[2]);
      acc[3] = fmaf(w3, bf2f(h3.y >> 16), acc[3]);
      acc[4] = fmaf(w3, bf2f(h3.z & 0xffffu), acc[4]);
      acc[5] = fmaf(w3, bf2f(h3.z >> 16), acc[5]);
      acc[6] = fmaf(w3, bf2f(h3.w & 0xffffu), acc[6]);
      acc[7] = fmaf(w3, bf2f(h3.w >> 16), acc[7]);
    }

    #pragma unroll
    for (int m = 8; m <= 16; m <<= 1) {
      #pragma unroll
      for (int j = 0; j < 8; ++j) acc[j] += __shfl_xor(acc[j], m);
    }

    const int n = n0 + dl;
    if (g == 0 && n < NN) {
      float r[8];
      #pragma unroll
      for (int j = 0; j < 8; ++j)
        r[j] = (acc[j] > 0.f) ? acc[j] : __expf(acc[j]) - 1.f;   // elu
      unsigned ob = ((unsigned)n << 6) + cl8;
      *reinterpret_cast<float4*>(&out[ob]) = make_float4(r[0], r[1], r[2], r[3]);
      *reinterpret_cast<float4*>(&out[ob + 4]) = make_float4(r[4], r[5], r[6], r[7]);
    }
  }
}

extern "C" void kernel_launch(void* const* d_in, const int* in_sizes, int n_in,
                              void* d_out, int out_size, void* d_ws, size_t ws_size,
                              hipStream_t stream) {
  const float* x = (const float*)d_in[0];
  const int* edge = (const int*)d_in[1];   // [2, E]: row 0 = src, row 1 = dst
  const float* W = (const float*)d_in[2];
  const float* a = (const float*)d_in[3];
  const int* srcIdx = edge;
  const int* dstIdx = edge + EE;
  float* out = (float*)d_out;

  // workspace layout (~22 MB)
  unsigned short* Wxh = (unsigned short*)d_ws;                     // N*64 bf16 = 12.8 MB
  unsigned* binned = (unsigned*)((char*)d_ws + (size_t)NN * OUTC * 2);  // NB*BCAP*4B = 8.0 MB
  int* gcursor = (int*)(binned + (size_t)NB * BCAP);               // NB
  float* s_i = (float*)(gcursor + NB);                             // N
  float* s_j = s_i + NN;                                           // N

  k_zero<<<1, 256, 0, stream>>>(gcursor);
  k_gb<<<NBLKG, 256, 0, stream>>>(x, W, a, Wxh, s_i, s_j, srcIdx, dstIdx, gcursor, binned);
  k_sa<<<NB, 512, 0, stream>>>(gcursor, binned, s_i, s_j, Wxh, out);
}